// Round 1
// baseline (183.191 us; speedup 1.0000x reference)
//
#include <hip/hip_runtime.h>

#define NROWS 4096
#define DIM   128
#define KCLS  4
#define TILE  64
#define MARGIN_F 0.02f
#define EPS_F    1e-12f

// ---------------- kernel 1: squared norms + positive distances ----------------
// one wave per anchor; lane holds 2 floats of the row.
__global__ void k_sqn_posd(const float* __restrict__ x,
                           float* __restrict__ sqn,
                           float* __restrict__ posd)
{
    const int wave = threadIdx.x >> 6;
    const int lane = threadIdx.x & 63;
    const int a = (blockIdx.x << 2) + wave;

    const float2* row = (const float2*)(x + (size_t)a * DIM);
    const float2 va = row[lane];
    float s = va.x * va.x + va.y * va.y;
#pragma unroll
    for (int off = 32; off; off >>= 1) s += __shfl_xor(s, off);
    if (lane == 0) sqn[a] = s;

    const int cs  = a & ~(KCLS - 1);
    const int pic = a & (KCLS - 1);
#pragma unroll
    for (int o = 0; o < KCLS - 1; o++) {
        const int p = cs + o + (o >= pic ? 1 : 0);
        const float2* prow = (const float2*)(x + (size_t)p * DIM);
        const float2 vp = prow[lane];
        float dp = va.x * vp.x + va.y * vp.y;
        float sp = vp.x * vp.x + vp.y * vp.y;
#pragma unroll
        for (int off = 32; off; off >>= 1) {
            dp += __shfl_xor(dp, off);
            sp += __shfl_xor(sp, off);
        }
        if (lane == 0) {
            const float d2 = s + sp - 2.f * dp;
            posd[a * 3 + o] = sqrtf(fmaxf(d2, EPS_F));
        }
    }
}

// ---------------- kernel 2: fused tiled Gram + hinge reduction ----------------
// grid (64,64); blocks with tj<ti exit (triangular). Each 64x64 tile handles
// ordered pairs (i,j); off-diagonal tiles also accumulate for anchor j
// (symmetry). k-major LDS [BK][64] -> conflict-free ds_read_b128 inner loop.
__global__ __launch_bounds__(256) void k_tiles(
    const float* __restrict__ x,
    const float* __restrict__ sqn,
    const float* __restrict__ posd,
    unsigned int* __restrict__ flags,      // per-anchor "has valid triplet"
    double* __restrict__ dsum,             // [0]=trip total, [1]=neg dist sum
    unsigned long long* __restrict__ gcnt) // num_valid
{
    const int ti = blockIdx.y, tj = blockIdx.x;
    if (tj < ti) return;

    __shared__ float As[TILE][TILE];   // [k][row], k-major
    __shared__ float Bs[TILE][TILE];
    __shared__ unsigned int jc[TILE];
    __shared__ float rblk[8];
    __shared__ unsigned int rcnt[4];

    const int t  = threadIdx.x;
    const int ty = t >> 4, tx = t & 15;
    const int ibase = ti * TILE, jbase = tj * TILE;

    if (t < TILE) jc[t] = 0u;

    float acc[4][4];
#pragma unroll
    for (int r = 0; r < 4; r++)
#pragma unroll
        for (int c = 0; c < 4; c++) acc[r][c] = 0.f;

    // two K-chunks of 64
    for (int kc2 = 0; kc2 < 2; kc2++) {
        if (kc2) __syncthreads();   // readers of previous chunk done
        // load+transpose: thread handles 4 float4 (row = t>>2, kc = 4*(t&3)+q)
#pragma unroll
        for (int q = 0; q < 4; q++) {
            const int f   = (t << 2) + q;
            const int row = f >> 4;
            const int kc  = f & 15;
            const int k0  = kc << 2;
            const float4 va = *(const float4*)(x + (size_t)(ibase + row) * DIM + kc2 * 64 + k0);
            As[k0 + 0][row] = va.x; As[k0 + 1][row] = va.y;
            As[k0 + 2][row] = va.z; As[k0 + 3][row] = va.w;
            const float4 vb = *(const float4*)(x + (size_t)(jbase + row) * DIM + kc2 * 64 + k0);
            Bs[k0 + 0][row] = vb.x; Bs[k0 + 1][row] = vb.y;
            Bs[k0 + 2][row] = vb.z; Bs[k0 + 3][row] = vb.w;
        }
        __syncthreads();

#pragma unroll 16
        for (int kk = 0; kk < 64; kk++) {
            const float4 av = *(const float4*)(&As[kk][ty << 2]);
            const float4 bv = *(const float4*)(&Bs[kk][tx << 2]);
            const float ar[4] = {av.x, av.y, av.z, av.w};
            const float br[4] = {bv.x, bv.y, bv.z, bv.w};
#pragma unroll
            for (int r = 0; r < 4; r++)
#pragma unroll
                for (int c = 0; c < 4; c++)
                    acc[r][c] = fmaf(ar[r], br[c], acc[r][c]);
        }
    }

    // ---------------- epilogue ----------------
    const int ib = ibase + (ty << 2);
    const int jb = jbase + (tx << 2);
    const bool diag = (ti == tj);

    float sqi[4], sqj[4], pdi[4][3], pdj[4][3];
#pragma unroll
    for (int r = 0; r < 4; r++) {
        sqi[r] = sqn[ib + r];
        sqj[r] = sqn[jb + r];
#pragma unroll
        for (int p = 0; p < 3; p++) {
            pdi[r][p] = posd[(ib + r) * 3 + p];
            pdj[r][p] = posd[(jb + r) * 3 + p];
        }
    }

    float tripsum = 0.f, negsum = 0.f;
    unsigned int cnt = 0;
    unsigned int icnt[4] = {0, 0, 0, 0};
    unsigned int jcl[4]  = {0, 0, 0, 0};

#pragma unroll
    for (int r = 0; r < 4; r++) {
#pragma unroll
        for (int c = 0; c < 4; c++) {
            const int i = ib + r, j = jb + c;
            if (diag && ((i >> 2) == (j >> 2))) continue;  // same class (incl. i==j)
            const float dd = sqrtf(fmaxf(sqi[r] + sqj[c] - 2.f * acc[r][c], EPS_F));
            negsum += dd;                       // anchor i
#pragma unroll
            for (int p = 0; p < 3; p++) {
                const float tr = pdi[r][p] + MARGIN_F - dd;
                if (tr > 0.f) { tripsum += tr; cnt++; icnt[r]++; }
            }
            if (!diag) {                        // anchor j (symmetric pair)
                negsum += dd;
#pragma unroll
                for (int p = 0; p < 3; p++) {
                    const float tr = pdj[c][p] + MARGIN_F - dd;
                    if (tr > 0.f) { tripsum += tr; cnt++; jcl[c]++; }
                }
            }
        }
    }

    // i-anchor flags: reduce across the 16 tx lanes (same wave, width-16 segments)
#pragma unroll
    for (int r = 0; r < 4; r++) {
        unsigned int v = icnt[r];
#pragma unroll
        for (int off = 8; off; off >>= 1) v += __shfl_down(v, off, 16);
        if (tx == 0 && v) atomicOr(&flags[ib + r], 1u);
    }

    // j-anchor flags via shared
#pragma unroll
    for (int c = 0; c < 4; c++)
        if (jcl[c]) atomicOr(&jc[(tx << 2) + c], 1u);

    // block scalar reduction: wave shfl then cross-wave via LDS
    float ts = tripsum, ns = negsum;
    unsigned int cc = cnt;
#pragma unroll
    for (int off = 32; off; off >>= 1) {
        ts += __shfl_down(ts, off);
        ns += __shfl_down(ns, off);
        cc += __shfl_down(cc, off);
    }
    const int w = t >> 6;
    if ((t & 63) == 0) { rblk[w] = ts; rblk[4 + w] = ns; rcnt[w] = cc; }
    __syncthreads();

    if (t < TILE && jc[t]) atomicOr(&flags[jbase + t], 1u);
    if (t == 0) {
        const double tot = (double)rblk[0] + rblk[1] + rblk[2] + rblk[3];
        const double neg = (double)rblk[4] + rblk[5] + rblk[6] + rblk[7];
        const unsigned long long ctot =
            (unsigned long long)rcnt[0] + rcnt[1] + rcnt[2] + rcnt[3];
        if (tot != 0.0)  atomicAdd(&dsum[0], tot);
        if (neg != 0.0)  atomicAdd(&dsum[1], neg);
        if (ctot)        atomicAdd(gcnt, ctot);
    }
}

// ---------------- kernel 3: finalize 4 outputs ----------------
__global__ void k_final(const float* __restrict__ posd,
                        const unsigned int* __restrict__ flags,
                        const double* __restrict__ dsum,
                        const unsigned long long* __restrict__ gcnt,
                        float* __restrict__ out)
{
    const int t = threadIdx.x; // 256 threads, 1 block
    double ps = 0.0;
    for (int idx = t; idx < NROWS * 3; idx += 256) ps += (double)posd[idx];
    unsigned int zc = 0;
    for (int idx = t; idx < NROWS; idx += 256) zc += (flags[idx] == 0u) ? 1u : 0u;

    __shared__ double sps[256];
    __shared__ unsigned int szc[256];
    sps[t] = ps; szc[t] = zc;
    __syncthreads();
    for (int off = 128; off; off >>= 1) {
        if (t < off) { sps[t] += sps[t + off]; szc[t] += szc[t + off]; }
        __syncthreads();
    }
    if (t == 0) {
        const unsigned long long c = *gcnt;
        const double total = dsum[0];
        const double negs  = dsum[1];
        out[0] = (float)(c > 0 ? total / (double)c : 0.0);
        out[1] = (float)((double)szc[0] / (double)NROWS);
        out[2] = (float)(sps[0] / ((double)NROWS * 3.0));
        out[3] = (float)(negs / ((double)NROWS * (double)(NROWS - KCLS)));
    }
}

extern "C" void kernel_launch(void* const* d_in, const int* in_sizes, int n_in,
                              void* d_out, int out_size, void* d_ws, size_t ws_size,
                              hipStream_t stream)
{
    const float* x = (const float*)d_in[0];
    float* out = (float*)d_out;
    char* ws = (char*)d_ws;

    // workspace layout (64B aligned chunks)
    double* dsum = (double*)ws;                                   // 16 B
    unsigned long long* gcnt = (unsigned long long*)(ws + 16);    // 8 B
    float* sqn  = (float*)(ws + 64);                              // 16 KB
    float* posd = (float*)(ws + 64 + 16384);                      // 48 KB
    unsigned int* flags = (unsigned int*)(ws + 64 + 16384 + 49152); // 16 KB

    hipMemsetAsync(ws, 0, 64 + 16384 + 49152 + 16384, stream);

    k_sqn_posd<<<NROWS / 4, 256, 0, stream>>>(x, sqn, posd);

    dim3 g2(NROWS / TILE, NROWS / TILE);
    k_tiles<<<g2, 256, 0, stream>>>(x, sqn, posd, flags, dsum, gcnt);

    k_final<<<1, 256, 0, stream>>>(posd, flags, dsum, gcnt, out);
}

// Round 5
// 181.567 us; speedup vs baseline: 1.0089x; 1.0089x over previous
//
#include <hip/hip_runtime.h>

#define NROWS 4096
#define DIM   128
#define KCLS  4
#define NT    64          // 64x64 tiles
#define MARGIN_F 0.02f
#define EPS_F    1e-12f

typedef unsigned short ushort_t;
typedef unsigned int   uint_t;
typedef __attribute__((ext_vector_type(8)))  short bf16x8;
typedef __attribute__((ext_vector_type(16))) float f32x16;

// async global->LDS, 16B per lane, wave-uniform LDS base + lane*16
__device__ __forceinline__ void gload_lds16(const void* g, void* l) {
    __builtin_amdgcn_global_load_lds(
        (const __attribute__((address_space(1))) unsigned int*)g,
        (__attribute__((address_space(3))) unsigned int*)l, 16, 0, 0);
}

// RNE float -> bf16, also return the back-converted float
__device__ __forceinline__ ushort_t rne_bf16(float v, float& back) {
    uint_t u = __float_as_uint(v);
    uint_t r = (u + 0x7fffu + ((u >> 16) & 1u)) >> 16;
    back = __uint_as_float(r << 16);
    return (ushort_t)r;
}

// ---------------- kernel 1: norms, pos distances, bf16 hi/lo split ----------
__global__ void k_prep(const float* __restrict__ x,
                       float* __restrict__ sqn,
                       float4* __restrict__ posd4,
                       ushort_t* __restrict__ xh,
                       ushort_t* __restrict__ xl)
{
    const int wave = threadIdx.x >> 6;
    const int lane = threadIdx.x & 63;
    const int a = (blockIdx.x << 2) + wave;

    const float2 va = ((const float2*)(x + (size_t)a * DIM))[lane];

    float hb0, hb1, lb0, lb1;
    const ushort_t h0 = rne_bf16(va.x, hb0);
    const ushort_t h1 = rne_bf16(va.y, hb1);
    const ushort_t l0 = rne_bf16(va.x - hb0, lb0);
    const ushort_t l1 = rne_bf16(va.y - hb1, lb1);
    ((uint_t*)xh)[a * 64 + lane] = (uint_t)h0 | ((uint_t)h1 << 16);
    ((uint_t*)xl)[a * 64 + lane] = (uint_t)l0 | ((uint_t)l1 << 16);

    float s = va.x * va.x + va.y * va.y;
#pragma unroll
    for (int off = 32; off; off >>= 1) s += __shfl_xor(s, off);
    if (lane == 0) sqn[a] = s;

    const int cs = a & ~(KCLS - 1), pic = a & (KCLS - 1);
    float pd[3];
#pragma unroll
    for (int o = 0; o < KCLS - 1; ++o) {
        const int p = cs + o + (o >= pic ? 1 : 0);
        const float2 vp = ((const float2*)(x + (size_t)p * DIM))[lane];
        float dp = va.x * vp.x + va.y * vp.y;
        float sp = vp.x * vp.x + vp.y * vp.y;
#pragma unroll
        for (int off = 32; off; off >>= 1) {
            dp += __shfl_xor(dp, off);
            sp += __shfl_xor(sp, off);
        }
        pd[o] = sqrtf(fmaxf(s + sp - 2.f * dp, EPS_F));
    }
    if (lane == 0) posd4[a] = make_float4(pd[0], pd[1], pd[2], 0.f);
}

// ---------------- kernel 2: MFMA Gram tiles + fused hinge ----------------
// 64x64 tile, 4 waves in 2x2 quadrants, each wave one 32x32 MFMA output.
// Gram = Xh.Xh^T + Xh.Xl^T + Xl.Xh^T  (ll dropped, ~2^-18 relative).
__global__ __launch_bounds__(256, 4) void k_tiles(
    const ushort_t* __restrict__ xh, const ushort_t* __restrict__ xl,
    const float* __restrict__ sqn, const float4* __restrict__ posd4,
    uint_t* __restrict__ flags, double* __restrict__ dsum,
    unsigned long long* __restrict__ gcnt)
{
    const int ti = blockIdx.y, tj = blockIdx.x;
    if (tj < ti) return;

    __shared__ ushort_t lds[4][64 * 64];  // Ah, Al, Bh, Bl chunks [64 rows][64 k] bf16
    __shared__ float rs[8];
    __shared__ uint_t rc[4];

    const int t    = threadIdx.x;
    const int wave = t >> 6, lane = t & 63;
    const int wr = wave >> 1, wc = wave & 1;
    const int col = lane & 31, hi = lane >> 5;
    const int ibase = ti << 6, jbase = tj << 6;
    const bool diag = (ti == tj);

    f32x16 acc;
#pragma unroll
    for (int r = 0; r < 16; ++r) acc[r] = 0.f;

    for (int kc = 0; kc < 2; ++kc) {
        if (kc) __syncthreads();
        // stage: LDS dest linear (unit u = row*8 + sp of 16B), global source
        // pre-swizzled: slot s = sp ^ (row&7)  (rule #21: inverse-swz source)
#pragma unroll
        for (int half = 0; half < 2; ++half) {
            const int u   = (half << 8) + (wave << 6) + lane;
            const int row = u >> 3, sp = u & 7;
            const int s   = sp ^ (row & 7);
            const size_t koff = (size_t)(kc << 6) + (s << 3);
            const int ldsb = ((half << 8) + (wave << 6)) << 3;   // ushort idx of wave base
            gload_lds16(xh + (size_t)(ibase + row) * DIM + koff, &lds[0][ldsb]);
            gload_lds16(xl + (size_t)(ibase + row) * DIM + koff, &lds[1][ldsb]);
            gload_lds16(xh + (size_t)(jbase + row) * DIM + koff, &lds[2][ldsb]);
            gload_lds16(xl + (size_t)(jbase + row) * DIM + koff, &lds[3][ldsb]);
        }
        __syncthreads();

        const int ar = (wr << 5) + col;   // A-frag row (lane&31)
        const int br = (wc << 5) + col;   // B-frag row
#pragma unroll
        for (int kk = 0; kk < 4; ++kk) {
            const int slot = (kk << 1) + hi;
            const int ao = (ar << 6) + ((slot ^ (ar & 7)) << 3);
            const int bo = (br << 6) + ((slot ^ (br & 7)) << 3);
            const bf16x8 ah = *(const bf16x8*)&lds[0][ao];
            const bf16x8 al = *(const bf16x8*)&lds[1][ao];
            const bf16x8 bh = *(const bf16x8*)&lds[2][bo];
            const bf16x8 bl = *(const bf16x8*)&lds[3][bo];
            acc = __builtin_amdgcn_mfma_f32_32x32x16_bf16(ah, bh, acc, 0, 0, 0);
            acc = __builtin_amdgcn_mfma_f32_32x32x16_bf16(ah, bl, acc, 0, 0, 0);
            acc = __builtin_amdgcn_mfma_f32_32x32x16_bf16(al, bh, acc, 0, 0, 0);
        }
    }

    // ---------------- epilogue: hinge + reductions ----------------
    const int jg = jbase + (wc << 5) + col;
    const float sqj = sqn[jg];
    const float4 pj = posd4[jg];

    float ts = 0.f, ns = 0.f;
    uint_t cnt = 0, jany = 0;

#pragma unroll
    for (int r = 0; r < 16; ++r) {
        const int rbase = (r & 3) + ((r >> 2) << 3);           // C/D row map (m74/m101)
        const int i = ibase + (wr << 5) + rbase + (hi << 2);
        const bool skip = diag && ((i >> 2) == (jg >> 2));      // same class (incl i==j)
        const float dd = sqrtf(fmaxf(sqn[i] + sqj - 2.f * acc[r], EPS_F));
        uint_t ia = 0;
        if (!skip) {
            ns += dd;                                           // anchor i
            const float4 pi = posd4[i];
            const float t0 = pi.x + MARGIN_F - dd;
            const float t1 = pi.y + MARGIN_F - dd;
            const float t2 = pi.z + MARGIN_F - dd;
            if (t0 > 0.f) { ts += t0; cnt++; ia = 1; }
            if (t1 > 0.f) { ts += t1; cnt++; ia = 1; }
            if (t2 > 0.f) { ts += t2; cnt++; ia = 1; }
            if (!diag) {                                        // anchor j (symmetric)
                ns += dd;
                const float u0 = pj.x + MARGIN_F - dd;
                const float u1 = pj.y + MARGIN_F - dd;
                const float u2 = pj.z + MARGIN_F - dd;
                if (u0 > 0.f) { ts += u0; cnt++; jany = 1; }
                if (u1 > 0.f) { ts += u1; cnt++; jany = 1; }
                if (u2 > 0.f) { ts += u2; cnt++; jany = 1; }
            }
        }
        // i-anchor flags: lanes 0..31 are hi=0 row, 32..63 are hi=1 row
        const unsigned long long m = __ballot(ia != 0);
        if (lane == 0 && (uint_t)(m & 0xffffffffull))
            atomicOr(&flags[ibase + (wr << 5) + rbase], 1u);
        if (lane == 32 && (uint_t)(m >> 32))
            atomicOr(&flags[ibase + (wr << 5) + rbase + 4], 1u);
    }
    if (!diag && jany) atomicOr(&flags[jg], 1u);

    // block scalar reduction
#pragma unroll
    for (int off = 32; off; off >>= 1) {
        ts  += __shfl_down(ts, off);
        ns  += __shfl_down(ns, off);
        cnt += __shfl_down(cnt, off);
    }
    if (lane == 0) { rs[wave] = ts; rs[4 + wave] = ns; rc[wave] = cnt; }
    __syncthreads();
    if (t == 0) {
        const double tot = (double)rs[0] + rs[1] + rs[2] + rs[3];
        const double neg = (double)rs[4] + rs[5] + rs[6] + rs[7];
        const unsigned long long c =
            (unsigned long long)rc[0] + rc[1] + rc[2] + rc[3];
        if (tot != 0.0) atomicAdd(&dsum[0], tot);
        atomicAdd(&dsum[1], neg);
        if (c) atomicAdd(gcnt, c);
    }
}

// ---------------- kernel 3: finalize ----------------
__global__ void k_final(const float4* __restrict__ posd4,
                        const uint_t* __restrict__ flags,
                        const double* __restrict__ dsum,
                        const unsigned long long* __restrict__ gcnt,
                        float* __restrict__ out)
{
    const int t = threadIdx.x;
    double ps = 0.0;
    for (int idx = t; idx < NROWS; idx += 256) {
        const float4 p = posd4[idx];
        ps += (double)p.x + (double)p.y + (double)p.z;
    }
    uint_t zc = 0;
    for (int idx = t; idx < NROWS; idx += 256) zc += (flags[idx] == 0u) ? 1u : 0u;

    __shared__ double sps[256];
    __shared__ uint_t szc[256];
    sps[t] = ps; szc[t] = zc;
    __syncthreads();
    for (int off = 128; off; off >>= 1) {
        if (t < off) { sps[t] += sps[t + off]; szc[t] += szc[t + off]; }
        __syncthreads();
    }
    if (t == 0) {
        const unsigned long long c = *gcnt;
        out[0] = (float)(c ? dsum[0] / (double)c : 0.0);
        out[1] = (float)((double)szc[0] / (double)NROWS);
        out[2] = (float)(sps[0] / ((double)NROWS * 3.0));
        out[3] = (float)(dsum[1] / ((double)NROWS * (double)(NROWS - KCLS)));
    }
}

extern "C" void kernel_launch(void* const* d_in, const int* in_sizes, int n_in,
                              void* d_out, int out_size, void* d_ws, size_t ws_size,
                              hipStream_t stream)
{
    const float* x = (const float*)d_in[0];
    float* out = (float*)d_out;
    char* ws = (char*)d_ws;

    // layout: [0,16) dsum, [16,24) gcnt, [64, +16K) flags,
    //         sqn 16K, posd4 64K, xh 1M, xl 1M   (~2.2 MB total)
    double* dsum = (double*)ws;
    unsigned long long* gcnt = (unsigned long long*)(ws + 16);
    uint_t* flags  = (uint_t*)(ws + 64);
    float*  sqn    = (float*)(ws + 64 + 16384);
    float4* posd4  = (float4*)(ws + 64 + 16384 + 16384);
    ushort_t* xh   = (ushort_t*)(ws + 64 + 16384 + 16384 + 65536);
    ushort_t* xl   = (ushort_t*)(ws + 64 + 16384 + 16384 + 65536 + 1048576);

    hipMemsetAsync(ws, 0, 64 + 16384, stream);   // dsum, gcnt, flags

    k_prep<<<NROWS / 4, 256, 0, stream>>>(x, sqn, posd4, xh, xl);

    dim3 g2(NT, NT);
    k_tiles<<<g2, 256, 0, stream>>>(xh, xl, sqn, posd4, flags, dsum, gcnt);

    k_final<<<1, 256, 0, stream>>>(posd4, flags, dsum, gcnt, out);
}

// Round 6
// 169.263 us; speedup vs baseline: 1.0823x; 1.0727x over previous
//
#include <hip/hip_runtime.h>

#define NROWS 4096
#define DIM   128
#define KCLS  4
#define NTILE 64                 // 64x64 anchor tiles
#define NTRI  2080               // NTILE*(NTILE+1)/2 triangular blocks
#define MARGIN_F 0.02f
#define EPS_F    1e-12f

typedef unsigned short ushort_t;
typedef unsigned int   uint_t;
typedef __attribute__((ext_vector_type(8)))  short bf16x8;
typedef __attribute__((ext_vector_type(16))) float f32x16;

__device__ __forceinline__ void gload_lds16(const void* g, void* l) {
    __builtin_amdgcn_global_load_lds(
        (const __attribute__((address_space(1))) unsigned int*)g,
        (__attribute__((address_space(3))) unsigned int*)l, 16, 0, 0);
}

__device__ __forceinline__ ushort_t rne_bf16(float v, float& back) {
    uint_t u = __float_as_uint(v);
    uint_t r = (u + 0x7fffu + ((u >> 16) & 1u)) >> 16;
    back = __uint_as_float(r << 16);
    return (ushort_t)r;
}

// ---------------- kernel 1: norms, pos distances, bf16 hi/lo split ----------
// block 0 additionally zeroes the imask/jmask words (256 words total).
__global__ void k_prep(const float* __restrict__ x,
                       float* __restrict__ sqn,
                       float4* __restrict__ posd4,
                       ushort_t* __restrict__ xh,
                       ushort_t* __restrict__ xl,
                       uint_t* __restrict__ imask,
                       uint_t* __restrict__ jmask)
{
    if (blockIdx.x == 0) {
        const int t = threadIdx.x;
        if (t < 128) imask[t] = 0u; else jmask[t - 128] = 0u;
    }
    const int wave = threadIdx.x >> 6;
    const int lane = threadIdx.x & 63;
    const int a = (blockIdx.x << 2) + wave;

    const float2 va = ((const float2*)(x + (size_t)a * DIM))[lane];

    float hb0, hb1, lb0, lb1;
    const ushort_t h0 = rne_bf16(va.x, hb0);
    const ushort_t h1 = rne_bf16(va.y, hb1);
    const ushort_t l0 = rne_bf16(va.x - hb0, lb0);
    const ushort_t l1 = rne_bf16(va.y - hb1, lb1);
    ((uint_t*)xh)[a * 64 + lane] = (uint_t)h0 | ((uint_t)h1 << 16);
    ((uint_t*)xl)[a * 64 + lane] = (uint_t)l0 | ((uint_t)l1 << 16);

    float s = va.x * va.x + va.y * va.y;
#pragma unroll
    for (int off = 32; off; off >>= 1) s += __shfl_xor(s, off);
    if (lane == 0) sqn[a] = s;

    const int cs = a & ~(KCLS - 1), pic = a & (KCLS - 1);
    float pd[3];
#pragma unroll
    for (int o = 0; o < KCLS - 1; ++o) {
        const int p = cs + o + (o >= pic ? 1 : 0);
        const float2 vp = ((const float2*)(x + (size_t)p * DIM))[lane];
        float dp = va.x * vp.x + va.y * vp.y;
        float sp = vp.x * vp.x + vp.y * vp.y;
#pragma unroll
        for (int off = 32; off; off >>= 1) {
            dp += __shfl_xor(dp, off);
            sp += __shfl_xor(sp, off);
        }
        pd[o] = sqrtf(fmaxf(s + sp - 2.f * dp, EPS_F));
    }
    if (lane == 0) posd4[a] = make_float4(pd[0], pd[1], pd[2], 0.f);
}

// ---------------- kernel 2: MFMA Gram tiles + fused hinge ----------------
// Triangular grid of NTRI blocks (no no-op half). No scalar atomics:
// each wave stores a private float4 partial. Flags via 3 mask-atomicOr/wave.
__global__ __launch_bounds__(256, 4) void k_tiles(
    const ushort_t* __restrict__ xh, const ushort_t* __restrict__ xl,
    const float* __restrict__ sqn, const float4* __restrict__ posd4,
    uint_t* __restrict__ imask, uint_t* __restrict__ jmask,
    float4* __restrict__ partial)
{
    // triangular decode: bid -> (ti, tj), tj >= ti
    const int bidp = (NTRI - 1) - (int)blockIdx.x;
    int m = (int)((sqrtf((float)(8 * bidp + 1)) - 1.0f) * 0.5f);
    while ((m + 1) * (m + 2) / 2 <= bidp) ++m;
    while (m * (m + 1) / 2 > bidp) --m;
    const int ti = (NTILE - 1) - m;
    const int tj = (NTILE - 1) - (bidp - m * (m + 1) / 2);

    __shared__ ushort_t lds[4][64 * 64];  // Ah, Al, Bh, Bl [64 rows][64 k] bf16

    const int t    = threadIdx.x;
    const int wave = t >> 6, lane = t & 63;
    const int wr = wave >> 1, wc = wave & 1;
    const int col = lane & 31, hi = lane >> 5;
    const int ibase = ti << 6, jbase = tj << 6;
    const bool diag = (ti == tj);

    f32x16 acc;
#pragma unroll
    for (int r = 0; r < 16; ++r) acc[r] = 0.f;

    for (int kc = 0; kc < 2; ++kc) {
        if (kc) __syncthreads();
        // LDS dest linear; global source pre-swizzled (rule #21)
#pragma unroll
        for (int half = 0; half < 2; ++half) {
            const int u   = (half << 8) + (wave << 6) + lane;
            const int row = u >> 3, sp = u & 7;
            const int s   = sp ^ (row & 7);
            const size_t koff = (size_t)(kc << 6) + (s << 3);
            const int ldsb = ((half << 8) + (wave << 6)) << 3;
            gload_lds16(xh + (size_t)(ibase + row) * DIM + koff, &lds[0][ldsb]);
            gload_lds16(xl + (size_t)(ibase + row) * DIM + koff, &lds[1][ldsb]);
            gload_lds16(xh + (size_t)(jbase + row) * DIM + koff, &lds[2][ldsb]);
            gload_lds16(xl + (size_t)(jbase + row) * DIM + koff, &lds[3][ldsb]);
        }
        __syncthreads();

        const int ar = (wr << 5) + col;
        const int br = (wc << 5) + col;
#pragma unroll
        for (int kk = 0; kk < 4; ++kk) {
            const int slot = (kk << 1) + hi;
            const int ao = (ar << 6) + ((slot ^ (ar & 7)) << 3);
            const int bo = (br << 6) + ((slot ^ (br & 7)) << 3);
            const bf16x8 ah = *(const bf16x8*)&lds[0][ao];
            const bf16x8 al = *(const bf16x8*)&lds[1][ao];
            const bf16x8 bh = *(const bf16x8*)&lds[2][bo];
            const bf16x8 bl = *(const bf16x8*)&lds[3][bo];
            acc = __builtin_amdgcn_mfma_f32_32x32x16_bf16(ah, bh, acc, 0, 0, 0);
            acc = __builtin_amdgcn_mfma_f32_32x32x16_bf16(ah, bl, acc, 0, 0, 0);
            acc = __builtin_amdgcn_mfma_f32_32x32x16_bf16(al, bh, acc, 0, 0, 0);
        }
    }

    // ---------------- epilogue ----------------
    // per-lane preloads: j-side (own column) and i-side (row = lane&31 of
    // this wave's 32-row band, broadcast later via shfl)
    const int jg = jbase + (wc << 5) + col;
    const float sqj = sqn[jg];
    const float4 pj = posd4[jg];
    const float sqi_l = sqn[ibase + (wr << 5) + col];      // lanes 0..31 & dup
    const float4 pi_l = posd4[ibase + (wr << 5) + col];

    float ts = 0.f, ns = 0.f;
    float cntf = 0.f;
    uint_t iam = 0;        // bit r: this lane's (r,hi) row had a valid triplet
    uint_t jany = 0;

    const int jcls = jg >> 2;
#pragma unroll
    for (int r = 0; r < 16; ++r) {
        const int rbase = (r & 3) + ((r >> 2) << 3);        // C/D row map
        const int src = rbase + (hi << 2);                  // row idx in band
        const float sqi = __shfl(sqi_l, src);
        const float p0  = __shfl(pi_l.x, src);
        const float p1  = __shfl(pi_l.y, src);
        const float p2  = __shfl(pi_l.z, src);
        const int i = ibase + (wr << 5) + src;
        const bool skip = diag && ((i >> 2) == jcls);
        const float dd = sqrtf(fmaxf(sqi + sqj - 2.f * acc[r], EPS_F));
        if (!skip) {
            ns += dd;                                       // anchor i
            const float t0 = p0 + MARGIN_F - dd;
            const float t1 = p1 + MARGIN_F - dd;
            const float t2 = p2 + MARGIN_F - dd;
            uint_t v = 0;
            if (t0 > 0.f) { ts += t0; cntf += 1.f; v = 1u; }
            if (t1 > 0.f) { ts += t1; cntf += 1.f; v = 1u; }
            if (t2 > 0.f) { ts += t2; cntf += 1.f; v = 1u; }
            iam |= v << r;
            if (!diag) {                                    // anchor j
                ns += dd;
                const float u0 = pj.x + MARGIN_F - dd;
                const float u1 = pj.y + MARGIN_F - dd;
                const float u2 = pj.z + MARGIN_F - dd;
                if (u0 > 0.f) { ts += u0; cntf += 1.f; jany = 1u; }
                if (u1 > 0.f) { ts += u1; cntf += 1.f; jany = 1u; }
                if (u2 > 0.f) { ts += u2; cntf += 1.f; jany = 1u; }
            }
        }
    }

    // i-flags: OR-reduce iam within each 32-lane half, remap r-bits->row-bits,
    // one atomicOr per half-wave.
    uint_t iam_all = iam;
#pragma unroll
    for (int off = 1; off < 32; off <<= 1) iam_all |= __shfl_xor(iam_all, off);
    uint_t rowmask = 0;
#pragma unroll
    for (int r = 0; r < 16; ++r)
        if ((iam_all >> r) & 1u)
            rowmask |= 1u << ((r & 3) + ((r >> 2) << 3) + (hi << 2));
    if (lane == 0 || lane == 32)
        if (rowmask) atomicOr(&imask[(ti << 1) + wr], rowmask);

    // j-flags: one ballot -> 32-bit column mask -> one atomicOr per wave
    const unsigned long long bm = __ballot(jany != 0);
    const uint_t jm = (uint_t)bm | (uint_t)(bm >> 32);
    if (lane == 0 && jm) atomicOr(&jmask[(tj << 1) + wc], jm);

    // scalar partials: private slot per wave, plain store (no atomics)
#pragma unroll
    for (int off = 32; off; off >>= 1) {
        ts   += __shfl_down(ts, off);
        ns   += __shfl_down(ns, off);
        cntf += __shfl_down(cntf, off);
    }
    if (lane == 0)
        partial[(blockIdx.x << 2) + wave] = make_float4(ts, ns, cntf, 0.f);
}

// ---------------- kernel 3: finalize ----------------
__global__ void k_final(const float4* __restrict__ posd4,
                        const uint_t* __restrict__ imask,
                        const uint_t* __restrict__ jmask,
                        const float4* __restrict__ partial,
                        float* __restrict__ out)
{
    const int t = threadIdx.x;   // 256 threads, 1 block
    double ts = 0.0, ns = 0.0, cnt = 0.0, ps = 0.0;
    uint_t zc = 0;

    for (int idx = t; idx < NTRI * 4; idx += 256) {
        const float4 p = partial[idx];
        ts += (double)p.x; ns += (double)p.y; cnt += (double)p.z;
    }
    for (int idx = t; idx < NROWS; idx += 256) {
        const float4 p = posd4[idx];
        ps += (double)p.x + (double)p.y + (double)p.z;
    }
    for (int idx = t; idx < NROWS / 32; idx += 256)
        zc += 32u - (uint_t)__popc(imask[idx] | jmask[idx]);

    __shared__ double s0[256], s1[256], s2[256], s3[256];
    __shared__ uint_t s4[256];
    s0[t] = ts; s1[t] = ns; s2[t] = cnt; s3[t] = ps; s4[t] = zc;
    __syncthreads();
    for (int off = 128; off; off >>= 1) {
        if (t < off) {
            s0[t] += s0[t + off]; s1[t] += s1[t + off];
            s2[t] += s2[t + off]; s3[t] += s3[t + off];
            s4[t] += s4[t + off];
        }
        __syncthreads();
    }
    if (t == 0) {
        const double c = s2[0];
        out[0] = (float)(c > 0.0 ? s0[0] / c : 0.0);
        out[1] = (float)((double)s4[0] / (double)NROWS);
        out[2] = (float)(s3[0] / ((double)NROWS * 3.0));
        out[3] = (float)(s1[0] / ((double)NROWS * (double)(NROWS - KCLS)));
    }
}

extern "C" void kernel_launch(void* const* d_in, const int* in_sizes, int n_in,
                              void* d_out, int out_size, void* d_ws, size_t ws_size,
                              hipStream_t stream)
{
    const float* x = (const float*)d_in[0];
    float* out = (float*)d_out;
    char* ws = (char*)d_ws;

    // workspace layout (aligned):
    // imask 512B | jmask 512B | sqn 16K | posd4 64K | partial 8320*16=133120 |
    // xh 1M | xl 1M
    uint_t* imask  = (uint_t*)ws;
    uint_t* jmask  = (uint_t*)(ws + 512);
    float*  sqn    = (float*)(ws + 1024);
    float4* posd4  = (float4*)(ws + 1024 + 16384);
    float4* partial= (float4*)(ws + 1024 + 16384 + 65536);
    ushort_t* xh   = (ushort_t*)(ws + 1024 + 16384 + 65536 + 133120);
    ushort_t* xl   = (ushort_t*)(ws + 1024 + 16384 + 65536 + 133120 + 1048576);

    k_prep<<<NROWS / 4, 256, 0, stream>>>(x, sqn, posd4, xh, xl, imask, jmask);
    k_tiles<<<NTRI, 256, 0, stream>>>(xh, xl, sqn, posd4, imask, jmask, partial);
    k_final<<<1, 256, 0, stream>>>(posd4, imask, jmask, partial, out);
}